// Round 11
// baseline (5002.485 us; speedup 1.0000x reference)
//
#include <hip/hip_runtime.h>

// HSMM forward log-likelihood, B=32, T=8192, K=128, Dmax=128.
// One block per sequence (32 blocks, 512 threads = 8 waves, 2/SIMD).
// R11 = R10 (verified, 4098us) with the step split around the barrier:
//   POST-barrier (depends on other waves' s(t-1)): 4x ds_read_b128 ->
//     matvec (16 pk, op_sel broadcast) -> ONE 3-stage DPP reduce (mp) ->
//     s = dp*psi + mp*beta -> ds_write_b64.
//   PRE-barrier tail (thread-local): ring insert, fold, duration dot for
//     t+1 (16 pk) + its reduce, ee rotation commit, logB b64 prefetch,
//     exp(logB), invpsi. All overlap the barrier/lgkmcnt dead window.
//   beta = expD0*(expB*rMp) uses invpsi(t-1)*psi(t) = expB*rMp, so the
//   combine needs no extra dependent muls after the mp reduce.
// State pairing is now ADJACENT (j = 2m, 2m+1), m = 8w + g, so the logB
// prefetch is one global_load_dwordx2. Gauge = 1-step proxy max (wave 0),
// clamp firewall, fold-every-16: R10 verbatim.

typedef float f32x2 __attribute__((ext_vector_type(2)));

#define T_LEN 8192
#define KST   128
#define NTHR  512
#define SROW  160   // shat buffer: 8 chunks x (16 data + 4 pad) floats

__device__ __forceinline__ void barrier_nodrain() {
  asm volatile("s_waitcnt lgkmcnt(0)\n\ts_barrier" ::: "memory");
}

template <int CTRL>
__device__ __forceinline__ float dpp_mov(float x) {
  int y = __builtin_amdgcn_update_dpp(0, __builtin_bit_cast(int, x),
                                      CTRL, 0xF, 0xF, true);
  return __builtin_bit_cast(float, y);
}
template <int CTRL>
__device__ __forceinline__ f32x2 dpp_addv(f32x2 x) {
  f32x2 y;
  y.x = dpp_mov<CTRL>(x.x);
  y.y = dpp_mov<CTRL>(x.y);
  return x + y;
}

__device__ __forceinline__ void pk_fma(f32x2& d, f32x2 a, f32x2 b) {
  asm("v_pk_fma_f32 %0, %1, %2, %0" : "+v"(d) : "v"(a), "v"(b));
}
// acc.lo += a.lo * b.lo; acc.hi += a.hi * b.lo   (broadcast b.lo)
__device__ __forceinline__ void pk_fma_blo(f32x2& d, f32x2 a, f32x2 b) {
  asm("v_pk_fma_f32 %0, %1, %2, %0 op_sel:[0,0,0] op_sel_hi:[1,0,1]"
      : "+v"(d) : "v"(a), "v"(b));
}
// acc.lo += a.lo * b.hi; acc.hi += a.hi * b.hi   (broadcast b.hi)
__device__ __forceinline__ void pk_fma_bhi(f32x2& d, f32x2 a, f32x2 b) {
  asm("v_pk_fma_f32 %0, %1, %2, %0 op_sel:[0,1,0] op_sel_hi:[1,1,1]"
      : "+v"(d) : "v"(a), "v"(b));
}
__device__ __forceinline__ f32x2 pk_mul(f32x2 a, f32x2 b) {
  f32x2 d;
  asm("v_pk_mul_f32 %0, %1, %2" : "=v"(d) : "v"(a), "v"(b));
  return d;
}

template <int U>
__device__ __forceinline__ void step_body(
    int t0, int cc, int w, int L, int sel, int c2, int cc16,
    const float* __restrict__ pB,
    f32x2 (&qq)[16], const f32x2 (&Apl)[8], const f32x2 (&Aph)[8],
    f32x2 (&ee)[16], f32x2 (&lbp)[16],
    int& off, f32x2& dpc,
    f32x2& psi, f32x2& invpsi, f32x2& exq, float& Ctot, f32x2& skeep,
    f32x2 expD0p, f32x2 pexpp, int swaddr,
    float* s_flat, float* m_sc, const float* ep_flat)
{
  const int t = t0 + U;
  const f32x2 expB = exq;  // exp(logB[t, pair]), computed last step

  // ======== POST-BARRIER: issue all loads up front ========
  // s(t-1): this chunk's 8 source-pairs (4 b128, conflict-free)
  const float* sp = s_flat + (U & 1) * SROW + 20 * cc;
  const float4 v0 = *(const float4*)(sp + 0),  v1 = *(const float4*)(sp + 4);
  const float4 v2 = *(const float4*)(sp + 8),  v3 = *(const float4*)(sp + 12);
  // gauge proxy max from step t-1 (1 b32 broadcast)
  float Mp = m_sc[U & 1];
  // ee rotation read for t+1 (constant table; committed in the tail)
  if (U == 15) {
    int rn = (t0 + 16 - cc16) & 127;
    int cl = (c2 + 4 * ((rn >> 4) & 7)) & 127;
    off = rn * 512 + cl * 4;
  } else {
    off = (off + 512) & 0xFFFF;
  }
  const f32x2 ne =
      *reinterpret_cast<const f32x2*>(reinterpret_cast<const char*>(ep_flat) + off);
  // logB pair prefetch t+16 (one b64 global load; 16-step slack)
  int tn = t + 16; tn = (tn < T_LEN) ? tn : (T_LEN - 1);
  lbp[U] = *reinterpret_cast<const f32x2*>(pB + (size_t)tn * KST);

  // matvec: 16 pk, dests (2m, 2m+1) in pk lanes, source-broadcast op_sel
  f32x2 ma = {0.0f, 0.0f}, mb = {0.0f, 0.0f};
  pk_fma_blo(ma, Apl[0], f32x2{v0.x, v0.y});  pk_fma_bhi(mb, Aph[0], f32x2{v0.x, v0.y});
  pk_fma_blo(ma, Apl[1], f32x2{v0.z, v0.w});  pk_fma_bhi(mb, Aph[1], f32x2{v0.z, v0.w});
  pk_fma_blo(ma, Apl[2], f32x2{v1.x, v1.y});  pk_fma_bhi(mb, Aph[2], f32x2{v1.x, v1.y});
  pk_fma_blo(ma, Apl[3], f32x2{v1.z, v1.w});  pk_fma_bhi(mb, Aph[3], f32x2{v1.z, v1.w});
  pk_fma_blo(ma, Apl[4], f32x2{v2.x, v2.y});  pk_fma_bhi(mb, Aph[4], f32x2{v2.x, v2.y});
  pk_fma_blo(ma, Apl[5], f32x2{v2.z, v2.w});  pk_fma_bhi(mb, Aph[5], f32x2{v2.z, v2.w});
  pk_fma_blo(ma, Apl[6], f32x2{v3.x, v3.y});  pk_fma_bhi(mb, Aph[6], f32x2{v3.x, v3.y});
  pk_fma_blo(ma, Apl[7], f32x2{v3.z, v3.w});  pk_fma_bhi(mb, Aph[7], f32x2{v3.z, v3.w});
  f32x2 mp = ma + mb;

  // reduce mp over 8 chunk lanes (the ONLY post-barrier reduce)
  mp = dpp_addv<0xB1>(mp); mp = dpp_addv<0x4E>(mp); mp = dpp_addv<0x141>(mp);

  // gauge scalars (parallel to the reduce)
  Mp = fminf(fmaxf(Mp, 1e-30f), 1e30f);   // exact free gauge; NaN firewall
  const float rMp = __builtin_amdgcn_rcpf(Mp);
  Ctot += __logf(Mp);
  const f32x2 er = pk_mul(expB, f32x2{rMp, rMp});  // expB*rMp
  psi = pk_mul(psi, er);
  const f32x2 beta = pk_mul(expD0p, er);           // expD0*invpsi_old*psi_new

  // s(t) = dp*psi + mp*beta  (dp was computed+reduced last step, pre-barrier)
  f32x2 Qins = pk_mul(mp, invpsi);
  f32x2 s = pk_mul(dpc, psi);
  pk_fma(s, mp, beta);
  if (U == 0) {
    if (t0 == 0) {                 // t == 0: dp = 0, start = pi
      Qins = pexpp;
      s = pk_mul(pk_mul(pexpp, expD0p), psi);
    }
  }

  // publish shat pair (one b64 per group) -- write EARLY
  if (cc == 0)
    *reinterpret_cast<f32x2*>(s_flat + ((U + 1) & 1) * SROW + swaddr) = s;

  // gauge proxy: wave 0's 16 states (verified DPP max chain)
  if (w == 0) {
    float sm = fmaxf(s.x, s.y);
    sm = fmaxf(sm, dpp_mov<0x140>(sm));   // row_mirror
    sm = fmaxf(sm, dpp_mov<0x142>(sm));   // row_bcast15
    sm = fmaxf(sm, dpp_mov<0x143>(sm));   // row_bcast31 -> lane 63
    if (L == 63) m_sc[(U + 1) & 1] = sm;
  }

  // ======== PRE-BARRIER TAIL (thread-local; fills the sync window) ========
  // ring insert: slot p = t&127 -> chunk sel = (t>>4)&7, reg U
  if (sel == cc) qq[U] = Qins;

  // fold gauge into ring every 16 steps
  if (U == 15) {
#pragma unroll
    for (int k = 0; k < 16; ++k) qq[k] = pk_mul(qq[k], psi);
    psi = f32x2{1.0f, 1.0f};
  }
  invpsi.x = __builtin_amdgcn_rcpf(psi.x);
  invpsi.y = __builtin_amdgcn_rcpf(psi.y);

  // commit ee rotation (old slot fully consumed by last step's dot)
  ee[(15 - U) & 15] = ne;

  // duration dot for t+1 (slots <= t all present) + its reduce
  f32x2 da = pk_mul(qq[0], ee[(0 - (U + 1)) & 15]);
  f32x2 db = pk_mul(qq[1], ee[(1 - (U + 1)) & 15]);
#pragma unroll
  for (int k = 2; k < 16; k += 2) {
    pk_fma(da, qq[k],     ee[(k - (U + 1)) & 15]);
    pk_fma(db, qq[k + 1], ee[(k + 1 - (U + 1)) & 15]);
  }
  dpc = da + db;
  dpc = dpp_addv<0xB1>(dpc); dpc = dpp_addv<0x4E>(dpc); dpc = dpp_addv<0x141>(dpc);

  // exp(logB) for t+1 (pair loaded 15 steps ago -> arrived)
  exq.x = __expf(lbp[(U + 1) & 15].x);
  exq.y = __expf(lbp[(U + 1) & 15].y);

  skeep = s;
  barrier_nodrain();
}

__global__ __launch_bounds__(NTHR, 1) void hsmm_fwd_kernel(
    const float* __restrict__ logB_all,
    const float* __restrict__ logpi,
    const float* __restrict__ logA,
    const float* __restrict__ logD,
    float* __restrict__ out)
{
  const int tid = threadIdx.x;
  const int L   = tid & 63;
  const int w   = tid >> 6;
  const int cc  = L & 7;            // source chunk (8 lanes per group)
  const int g   = L >> 3;           // dest group 0..7
  const int m   = 8 * w + g;        // pair index: states (2m, 2m+1)
  const int j0  = 2 * m;
  const int b   = blockIdx.x;
  const float* __restrict__ pB = logB_all + (size_t)b * T_LEN * KST + j0;

  // epair[d][col(m,d) + {0,1}] = (expD[2m][d], expD[2m+1][d]);
  // col(m,d) = (2m + 4*((d>>4)&7)) & 127. Row 0 zeroed (stale-slot kill).
  __shared__ __align__(16) float epair[128 * 128];
  __shared__ __align__(16) float s_lds[2 * SROW];  // padded pair-interleaved
  __shared__ float m_sc[2];                        // gauge proxy, dbuf
  __shared__ float fin[8];

  // ---- init ----
  for (int idx = tid; idx < 128 * 128; idx += NTHR) {
    int d = idx >> 7, r = idx & 127;
    int mm = r >> 1, hb = r & 1;
    int col = ((2 * mm + 4 * ((d >> 4) & 7)) & 127) + hb;
    epair[(d << 7) + col] = (d == 0) ? 0.0f : __expf(logD[(2 * mm + hb) * 128 + d]);
  }
  if (tid < 2 * SROW) s_lds[tid] = 0.0f;
  if (tid < 2) m_sc[tid] = 1.0f;

  // matvec constants: chunk cc covers source pairs mm = 8cc+k -> states
  // (16cc+2k, 16cc+2k+1). Apl = even-source coeffs, Aph = odd-source.
  f32x2 Apl[8], Aph[8];
#pragma unroll
  for (int k = 0; k < 8; ++k) {
    int se = 16 * cc + 2 * k;
    Apl[k].x = __expf(logA[se * KST + j0]);
    Apl[k].y = __expf(logA[se * KST + j0 + 1]);
    Aph[k].x = __expf(logA[(se + 1) * KST + j0]);
    Aph[k].y = __expf(logA[(se + 1) * KST + j0 + 1]);
  }
  const f32x2 expD0p = {__expf(logD[j0 * 128]), __expf(logD[(j0 + 1) * 128])};
  const f32x2 pexpp  = {__expf(logpi[j0]), __expf(logpi[j0 + 1])};
  const int   swaddr = 20 * w + 2 * g;   // pair m at 20*(m>>3) + 2*(m&7)
  const int   c2     = 2 * m;            // epair column base
  const int   cc16   = 16 * cc;

  f32x2 qq[16];
#pragma unroll
  for (int k = 0; k < 16; ++k) qq[k] = f32x2{0.0f, 0.0f};

  __syncthreads();  // table + buffers ready

  // ee init for t=0: ee[k] = epair row (-(16cc+k))&127, col base c2
  f32x2 ee[16];
#pragma unroll
  for (int k = 0; k < 16; ++k) {
    int rA = (-(cc16 + k)) & 127;
    int cl = (c2 + 4 * ((rA >> 4) & 7)) & 127;
    ee[k] = *reinterpret_cast<const f32x2*>(&epair[(rA << 7) + cl]);
  }

  // rotation byte offset, pre-decremented (body adds 512 -> row t+1-16cc)
  int off;
  {
    int r0 = (-cc16) & 127;
    int cl = (c2 + 4 * ((r0 >> 4) & 7)) & 127;
    off = r0 * 512 + cl * 4;
  }

  // logB pair prefetch ring (16 ahead)
  f32x2 lbp[16];
#pragma unroll
  for (int u = 0; u < 16; ++u)
    lbp[u] = *reinterpret_cast<const f32x2*>(pB + (size_t)u * KST);

  f32x2 psi = {1.0f, 1.0f}, invpsi = {1.0f, 1.0f};
  f32x2 dpc = {0.0f, 0.0f};          // dot for t=0 (ring empty)
  float Ctot = 0.0f;
  f32x2 skeep = {0.0f, 0.0f};
  f32x2 exq = {__expf(lbp[0].x), __expf(lbp[0].y)};

#pragma unroll 1
  for (int t0 = 0; t0 < T_LEN; t0 += 16) {
    const int sel = (t0 >> 4) & 7;   // ring chunk receiving this block
#define STEP(U) step_body<U>(t0, cc, w, L, sel, c2, cc16, pB, qq, Apl, Aph,   \
                             ee, lbp, off, dpc, psi, invpsi, exq, Ctot,       \
                             skeep, expD0p, pexpp, swaddr, s_lds, m_sc, epair)
    STEP(0);  STEP(1);  STEP(2);  STEP(3);
    STEP(4);  STEP(5);  STEP(6);  STEP(7);
    STEP(8);  STEP(9);  STEP(10); STEP(11);
    STEP(12); STEP(13); STEP(14); STEP(15);
#undef STEP
  }

  // ---- final: out[b] = Ctot + log sum_j shat[j] (each pair once: cc==0) --
  float v = (cc == 0) ? (skeep.x + skeep.y) : 0.0f;
  v += __shfl_xor(v, 8);  v += __shfl_xor(v, 16); v += __shfl_xor(v, 32);
  if (L == 0) fin[w] = v;
  __syncthreads();
  if (tid == 0) {
    float tot = 0.0f;
#pragma unroll
    for (int i = 0; i < 8; ++i) tot += fin[i];
    out[b] = Ctot + __logf(tot);
  }
}

extern "C" void kernel_launch(void* const* d_in, const int* in_sizes, int n_in,
                              void* d_out, int out_size, void* d_ws, size_t ws_size,
                              hipStream_t stream) {
  const float* logB  = (const float*)d_in[0];
  const float* logpi = (const float*)d_in[1];
  const float* logA  = (const float*)d_in[2];
  const float* logD  = (const float*)d_in[3];
  float* out = (float*)d_out;
  const int B = out_size;  // 32
  hipLaunchKernelGGL(hsmm_fwd_kernel, dim3(B), dim3(NTHR), 0, stream,
                     logB, logpi, logA, logD, out);
}

// Round 13
// 4396.124 us; speedup vs baseline: 1.1379x; 1.1379x over previous
//
#include <hip/hip_runtime.h>

// HSMM forward log-likelihood, B=32, T=8192, K=128, Dmax=128.
// One block per sequence (32 blocks, 512 threads = 8 waves, 2/SIMD).
// R13 = R10 (verified, 4098us, absmax 0.0) + two chain cuts:
//   1. bf16 shat exchange: pair (s_m, s_{m+64}) packed to one u32 via
//      v_cvt_pk_bf16_f32; s-reads 4->2 ds_read_b128/wave, write b64->b32.
//      Ring/gauge/output stay f32 (bf16 only in the cross-state mixing;
//      ~0.2% rel/step, random-sign -> ~1 nat total, threshold 272).
//   2. Damped 2-step gauge: dC_t = 0.5*x_{t-2} (rMp = rsqrt(Mp), Ctot +=
//      0.5*log Mp, m_sc depth 4). Poles (1+-i)/2, |z|=0.707: STABLE
//      (R2-R4's NaN was alpha=1, |z|=1 undamped). Max-chain+write now has
//      a full step of slack -> off the step tail.
// Lane layout (R10): cc = L&7 (source chunk), g = L>>3, pair m = 8w+g,
// states (j0, j1) = (m, m+64). Ring slots [16cc,16cc+16) as pairs qq[16];
// ee[16] rotating expD window; lb 16-deep logB prefetch.

typedef float f32x2 __attribute__((ext_vector_type(2)));
typedef unsigned int u32x4 __attribute__((ext_vector_type(4)));

#define T_LEN 8192
#define KST   128
#define NTHR  512
#define SROWU 96    // u32s per shat buffer: 8 groups x (8 data + 4 pad), 16B-aligned groups

__device__ __forceinline__ void barrier_nodrain() {
  asm volatile("s_waitcnt lgkmcnt(0)\n\ts_barrier" ::: "memory");
}

template <int CTRL>
__device__ __forceinline__ float dpp_mov(float x) {
  int y = __builtin_amdgcn_update_dpp(0, __builtin_bit_cast(int, x),
                                      CTRL, 0xF, 0xF, true);
  return __builtin_bit_cast(float, y);
}
template <int CTRL>
__device__ __forceinline__ f32x2 dpp_addv(f32x2 x) {
  f32x2 y;
  y.x = dpp_mov<CTRL>(x.x);
  y.y = dpp_mov<CTRL>(x.y);
  return x + y;
}

__device__ __forceinline__ void pk_fma(f32x2& d, f32x2 a, f32x2 b) {
  asm("v_pk_fma_f32 %0, %1, %2, %0" : "+v"(d) : "v"(a), "v"(b));
}
// acc.lo += a.lo * b.lo; acc.hi += a.hi * b.lo   (broadcast b.lo)
__device__ __forceinline__ void pk_fma_blo(f32x2& d, f32x2 a, f32x2 b) {
  asm("v_pk_fma_f32 %0, %1, %2, %0 op_sel:[0,0,0] op_sel_hi:[1,0,1]"
      : "+v"(d) : "v"(a), "v"(b));
}
// acc.lo += a.lo * b.hi; acc.hi += a.hi * b.hi   (broadcast b.hi)
__device__ __forceinline__ void pk_fma_bhi(f32x2& d, f32x2 a, f32x2 b) {
  asm("v_pk_fma_f32 %0, %1, %2, %0 op_sel:[0,1,0] op_sel_hi:[1,1,1]"
      : "+v"(d) : "v"(a), "v"(b));
}
__device__ __forceinline__ f32x2 pk_mul(f32x2 a, f32x2 b) {
  f32x2 d;
  asm("v_pk_mul_f32 %0, %1, %2" : "=v"(d) : "v"(a), "v"(b));
  return d;
}
// unpack bf16 pair (lo,hi) of u32 -> f32x2 (exact: bf16 occupies high bits)
__device__ __forceinline__ f32x2 bf2(unsigned int u) {
  f32x2 r;
  r.x = __builtin_bit_cast(float, u << 16);
  r.y = __builtin_bit_cast(float, u & 0xFFFF0000u);
  return r;
}

template <int U>
__device__ __forceinline__ void step_body(
    int t0, int cc, int w, int L, int sel, int c2, int cc16,
    const float* __restrict__ pB0, const float* __restrict__ pB1,
    f32x2 (&qq)[16], const f32x2 (&Apl)[8], const f32x2 (&Aph)[8],
    f32x2 (&ee)[16], float (&lb0)[16], float (&lb1)[16],
    int& off,
    f32x2& psi, f32x2& invpsi, f32x2& exq, float& Ctot, f32x2& skeep,
    f32x2 expD0p, f32x2 pexpp, int swaddr,
    unsigned int* s_flat, float* m_sc, const float* ep_flat)
{
  const int t = t0 + U;
  const f32x2 expB = exq;   // exp(logB[t, j0/j1]), computed last step

  // ---- issue memory early (R10 ordering) ----
  int tn = t + 16; tn = (tn < T_LEN) ? tn : (T_LEN - 1);
  lb0[U] = pB0[(size_t)tn * KST];
  lb1[U] = pB1[(size_t)tn * KST];

  // gauge proxy max from step t-2 (damped alpha=1/2 -> stable)
  float Mp = m_sc[U & 3];

  // shat(t-1): 8 bf16-pairs of this chunk (2 ds_read_b128, conflict-free)
  const unsigned int* sp = s_flat + (U & 1) * SROWU + 12 * cc;
  const u32x4 q0 = *(const u32x4*)(sp + 0);
  const u32x4 q1 = *(const u32x4*)(sp + 4);

  // ee rotation read for t+1 (byte-offset walk; skew changes at U==15)
  if (U == 15) {
    int rn = (t0 + 16 - cc16) & 127;
    int cl = (c2 + 4 * ((rn >> 4) & 7)) & 127;
    off = rn * 512 + cl * 4;
  } else {
    off = (off + 512) & 0xFFFF;
  }
  const f32x2 ne =
      *reinterpret_cast<const f32x2*>(reinterpret_cast<const char*>(ep_flat) + off);

  // ---- duration dot: 16 pk over state-paired ring (2 chains) ----
  f32x2 da = pk_mul(qq[0], ee[(0 - U) & 15]);
  f32x2 db = pk_mul(qq[1], ee[(1 - U) & 15]);
#pragma unroll
  for (int k = 2; k < 16; k += 2) {
    pk_fma(da, qq[k],     ee[(k - U) & 15]);
    pk_fma(db, qq[k + 1], ee[(k + 1 - U) & 15]);
  }
  f32x2 dp = da + db;

  // ---- gauge update: half-strength correction (exact free gauge) ----
  Mp = fminf(fmaxf(Mp, 1e-30f), 1e30f);
  const float rMp = __builtin_amdgcn_rsqf(Mp);   // Mp^-0.5
  Ctot += 0.5f * __logf(Mp);
  const f32x2 rv = {rMp, rMp};
  psi = pk_mul(psi, pk_mul(expB, rv));

  // ---- matvec: 16 pk, dests (j0,j1) in pk lanes, src-broadcast op_sel ----
  f32x2 ma = {0.0f, 0.0f}, mb = {0.0f, 0.0f};
  { f32x2 vp = bf2(q0.x); pk_fma_blo(ma, Apl[0], vp); pk_fma_bhi(mb, Aph[0], vp); }
  { f32x2 vp = bf2(q0.y); pk_fma_blo(ma, Apl[1], vp); pk_fma_bhi(mb, Aph[1], vp); }
  { f32x2 vp = bf2(q0.z); pk_fma_blo(ma, Apl[2], vp); pk_fma_bhi(mb, Aph[2], vp); }
  { f32x2 vp = bf2(q0.w); pk_fma_blo(ma, Apl[3], vp); pk_fma_bhi(mb, Aph[3], vp); }
  { f32x2 vp = bf2(q1.x); pk_fma_blo(ma, Apl[4], vp); pk_fma_bhi(mb, Aph[4], vp); }
  { f32x2 vp = bf2(q1.y); pk_fma_blo(ma, Apl[5], vp); pk_fma_bhi(mb, Aph[5], vp); }
  { f32x2 vp = bf2(q1.z); pk_fma_blo(ma, Apl[6], vp); pk_fma_bhi(mb, Aph[6], vp); }
  { f32x2 vp = bf2(q1.w); pk_fma_blo(ma, Apl[7], vp); pk_fma_bhi(mb, Aph[7], vp); }
  f32x2 mp = ma + mb;

  // ---- reduce over 8 chunk lanes (bits 0..2): xor1, xor2, mirror-8 ----
  dp = dpp_addv<0xB1>(dp); dp = dpp_addv<0x4E>(dp); dp = dpp_addv<0x141>(dp);
  mp = dpp_addv<0xB1>(mp); mp = dpp_addv<0x4E>(mp); mp = dpp_addv<0x141>(mp);

  // ---- insert pair + shat pair (group-uniform) ----
  f32x2 Qins = pk_mul(mp, invpsi);
  if (U == 0) { if (t0 == 0) Qins = pexpp; }
  f32x2 sacc = dp;
  pk_fma(sacc, Qins, expD0p);
  const f32x2 s = pk_mul(sacc, psi);

  // publish shat pair early: one u32 (bf16x2) per group
  if (cc == 0) {
    unsigned int pk;
    asm("v_cvt_pk_bf16_f32 %0, %1, %2" : "=v"(pk) : "v"(s.x), "v"(s.y));
    s_flat[((U + 1) & 1) * SROWU + swaddr] = pk;
  }

  // gauge proxy: wave 0's 16 states; written 2 steps ahead (full slack)
  if (w == 0) {
    float sm = fmaxf(s.x, s.y);
    sm = fmaxf(sm, dpp_mov<0x140>(sm));   // row_mirror
    sm = fmaxf(sm, dpp_mov<0x142>(sm));   // row_bcast15
    sm = fmaxf(sm, dpp_mov<0x143>(sm));   // row_bcast31 -> lane 63
    if (L == 63) m_sc[(U + 2) & 3] = sm;
  }

  // ---- thread-local tail ----
  // exp for NEXT step (loaded 15 steps ago -> arrived)
  exq.x = __expf(lb0[(U + 1) & 15]);
  exq.y = __expf(lb1[(U + 1) & 15]);

  // ring insert: slot p = t&127 -> chunk sel = (t>>4)&7, reg U
  if (sel == cc) qq[U] = Qins;

  // commit ee rotation (old slot fully consumed by the dot above)
  ee[(15 - U) & 15] = ne;

  // fold gauge into ring every 16 steps
  if (U == 15) {
#pragma unroll
    for (int k = 0; k < 16; ++k) qq[k] = pk_mul(qq[k], psi);
    psi = f32x2{1.0f, 1.0f};
  }
  invpsi.x = __builtin_amdgcn_rcpf(psi.x);
  invpsi.y = __builtin_amdgcn_rcpf(psi.y);

  skeep = s;
  barrier_nodrain();
}

__global__ __launch_bounds__(NTHR, 1) void hsmm_fwd_kernel(
    const float* __restrict__ logB_all,
    const float* __restrict__ logpi,
    const float* __restrict__ logA,
    const float* __restrict__ logD,
    float* __restrict__ out)
{
  const int tid = threadIdx.x;
  const int L   = tid & 63;
  const int w   = tid >> 6;
  const int cc  = L & 7;            // source chunk (8 lanes per group)
  const int g   = L >> 3;           // dest group 0..7
  const int j0  = 8 * w + g;        // state pair (j0, j0+64)
  const int j1  = j0 + 64;
  const int b   = blockIdx.x;
  const float* __restrict__ pB0 = logB_all + (size_t)b * T_LEN * KST + j0;
  const float* __restrict__ pB1 = pB0 + 64;

  // epair[d][(2j + 4*((d>>4)&7))&127 (+1)] = (expD[j][d], expD[j+64][d]);
  // row 0 zeroed (stale-slot kill). Skew -> conflict-free rotation reads.
  __shared__ __align__(16) float epair[128 * 128];
  __shared__ __align__(16) unsigned int s_lds[2 * SROWU];  // bf16x2 shat, dbuf
  __shared__ float m_sc[4];                                // gauge proxy, depth 4
  __shared__ float fin[8];

  // ---- init ----
  for (int idx = tid; idx < 128 * 128; idx += NTHR) {
    int d = idx >> 7, r = idx & 127;
    int j = r >> 1, hb = r & 1;
    int col = ((2 * j + 4 * ((d >> 4) & 7)) & 127) + hb;
    epair[(d << 7) + col] = (d == 0) ? 0.0f : __expf(logD[(j + 64 * hb) * 128 + d]);
  }
  if (tid < 2 * SROWU) s_lds[tid] = 0u;
  if (tid < 4) m_sc[tid] = 1.0f;

  // matvec constants: chunk cc covers source pairs m = 8cc+k, k=0..7
  f32x2 Apl[8], Aph[8];
#pragma unroll
  for (int k = 0; k < 8; ++k) {
    int m = 8 * cc + k;
    Apl[k].x = __expf(logA[m * KST + j0]);
    Apl[k].y = __expf(logA[m * KST + j1]);
    Aph[k].x = __expf(logA[(m + 64) * KST + j0]);
    Aph[k].y = __expf(logA[(m + 64) * KST + j1]);
  }
  const f32x2 expD0p = {__expf(logD[j0 * 128]), __expf(logD[j1 * 128])};
  const f32x2 pexpp  = {__expf(logpi[j0]), __expf(logpi[j1])};
  const int   swaddr = 12 * w + g;       // u32 slot of pair m = 8w+g
  const int   c2     = 16 * w + 2 * g;   // epair column base (2*j0)
  const int   cc16   = 16 * cc;

  f32x2 qq[16];
#pragma unroll
  for (int k = 0; k < 16; ++k) qq[k] = f32x2{0.0f, 0.0f};

  __syncthreads();  // table + buffers ready

  // ee init for t=0: ee[k] = epair row (-(16cc+k))&127, col base c2
  f32x2 ee[16];
#pragma unroll
  for (int k = 0; k < 16; ++k) {
    int rA = (-(cc16 + k)) & 127;
    int cl = (c2 + 4 * ((rA >> 4) & 7)) & 127;
    ee[k] = *reinterpret_cast<const f32x2*>(&epair[(rA << 7) + cl]);
  }

  // rotation byte offset, pre-decremented (body adds 512 -> row t+1-16cc)
  int off;
  {
    int r0 = (-cc16) & 127;
    int cl = (c2 + 4 * ((r0 >> 4) & 7)) & 127;
    off = r0 * 512 + cl * 4;
  }

  // logB prefetch rings (16 ahead)
  float lb0[16], lb1[16];
#pragma unroll
  for (int u = 0; u < 16; ++u) {
    lb0[u] = pB0[(size_t)u * KST];
    lb1[u] = pB1[(size_t)u * KST];
  }

  f32x2 psi = {1.0f, 1.0f}, invpsi = {1.0f, 1.0f};
  float Ctot = 0.0f;
  f32x2 skeep = {0.0f, 0.0f};
  f32x2 exq = {__expf(lb0[0]), __expf(lb1[0])};

#pragma unroll 1
  for (int t0 = 0; t0 < T_LEN; t0 += 16) {
    const int sel = (t0 >> 4) & 7;   // ring chunk receiving this block
#define STEP(U) step_body<U>(t0, cc, w, L, sel, c2, cc16, pB0, pB1, qq,       \
                             Apl, Aph, ee, lb0, lb1, off, psi, invpsi, exq,   \
                             Ctot, skeep, expD0p, pexpp, swaddr,              \
                             s_lds, m_sc, epair)
    STEP(0);  STEP(1);  STEP(2);  STEP(3);
    STEP(4);  STEP(5);  STEP(6);  STEP(7);
    STEP(8);  STEP(9);  STEP(10); STEP(11);
    STEP(12); STEP(13); STEP(14); STEP(15);
#undef STEP
  }

  // ---- final: out[b] = Ctot + log sum_j shat[j] (each pair once: cc==0) --
  float v = (cc == 0) ? (skeep.x + skeep.y) : 0.0f;
  v += __shfl_xor(v, 8);  v += __shfl_xor(v, 16); v += __shfl_xor(v, 32);
  if (L == 0) fin[w] = v;
  __syncthreads();
  if (tid == 0) {
    float tot = 0.0f;
#pragma unroll
    for (int i = 0; i < 8; ++i) tot += fin[i];
    out[b] = Ctot + __logf(tot);
  }
}

extern "C" void kernel_launch(void* const* d_in, const int* in_sizes, int n_in,
                              void* d_out, int out_size, void* d_ws, size_t ws_size,
                              hipStream_t stream) {
  const float* logB  = (const float*)d_in[0];
  const float* logpi = (const float*)d_in[1];
  const float* logA  = (const float*)d_in[2];
  const float* logD  = (const float*)d_in[3];
  float* out = (float*)d_out;
  const int B = out_size;  // 32
  hipLaunchKernelGGL(hsmm_fwd_kernel, dim3(B), dim3(NTHR), 0, stream,
                     logB, logpi, logA, logD, out);
}

// Round 15
// 3312.498 us; speedup vs baseline: 1.5102x; 1.3271x over previous
//
#include <hip/hip_runtime.h>

// HSMM forward log-likelihood, B=32, T=8192, K=128, Dmax=128.
// One block per sequence (32 blocks, 512 threads = 8 waves, 2/SIMD).
// R15 = R14 with the compile fix (__exp2f -> __builtin_amdgcn_exp2f).
//   1. SLOW GAUGE: per-16-step renorm constant K = M^(-1/16) (M = wave-0
//      proxy max read once per block; written once per block at U==15 by
//      the R10-verified DPP max chain). Per-step gauge = one pk_mul by
//      in-register Kv -- the per-step m_sc LDS read + clamp + rcp + logf
//      leave the critical head entirely. Free-gauge exact; residual drift
//      is zero-mean noise deadbeat-corrected per block (|x| < ~10 nats).
//   2. ADJACENT pairing (j = 2m, 2m+1; R11-verified layout): logB prefetch
//      is one b64 load; epair/A layouts R11-verbatim. Dot ordering = R10.
// Lane layout: cc = L&7 (source chunk), g = L>>3, pair m = 8w+g.
// Ring slots [16cc,16cc+16) as pairs qq[16]; ee[16] rotating expD window.

typedef float f32x2 __attribute__((ext_vector_type(2)));

#define T_LEN 8192
#define KST   128
#define NTHR  512
#define SROW  160   // shat buffer: 8 groups x (16 data + 4 pad) floats

__device__ __forceinline__ void barrier_nodrain() {
  asm volatile("s_waitcnt lgkmcnt(0)\n\ts_barrier" ::: "memory");
}

template <int CTRL>
__device__ __forceinline__ float dpp_mov(float x) {
  int y = __builtin_amdgcn_update_dpp(0, __builtin_bit_cast(int, x),
                                      CTRL, 0xF, 0xF, true);
  return __builtin_bit_cast(float, y);
}
template <int CTRL>
__device__ __forceinline__ f32x2 dpp_addv(f32x2 x) {
  f32x2 y;
  y.x = dpp_mov<CTRL>(x.x);
  y.y = dpp_mov<CTRL>(x.y);
  return x + y;
}

__device__ __forceinline__ void pk_fma(f32x2& d, f32x2 a, f32x2 b) {
  asm("v_pk_fma_f32 %0, %1, %2, %0" : "+v"(d) : "v"(a), "v"(b));
}
// acc.lo += a.lo * b.lo; acc.hi += a.hi * b.lo   (broadcast b.lo)
__device__ __forceinline__ void pk_fma_blo(f32x2& d, f32x2 a, f32x2 b) {
  asm("v_pk_fma_f32 %0, %1, %2, %0 op_sel:[0,0,0] op_sel_hi:[1,0,1]"
      : "+v"(d) : "v"(a), "v"(b));
}
// acc.lo += a.lo * b.hi; acc.hi += a.hi * b.hi   (broadcast b.hi)
__device__ __forceinline__ void pk_fma_bhi(f32x2& d, f32x2 a, f32x2 b) {
  asm("v_pk_fma_f32 %0, %1, %2, %0 op_sel:[0,1,0] op_sel_hi:[1,1,1]"
      : "+v"(d) : "v"(a), "v"(b));
}
__device__ __forceinline__ f32x2 pk_mul(f32x2 a, f32x2 b) {
  f32x2 d;
  asm("v_pk_mul_f32 %0, %1, %2" : "=v"(d) : "v"(a), "v"(b));
  return d;
}

template <int U>
__device__ __forceinline__ void step_body(
    int t0, int cc, int w, int L, int sel, int c2, int cc16,
    const float* __restrict__ pB,
    f32x2 (&qq)[16], const f32x2 (&Apl)[8], const f32x2 (&Aph)[8],
    f32x2 (&ee)[16], f32x2 (&lbp)[16],
    int& off,
    f32x2& psi, f32x2& invpsi, f32x2& exq, f32x2& Kv,
    float& Ctot, f32x2& skeep,
    f32x2 expD0p, f32x2 pexpp, int swaddr,
    float* s_flat, float* m_sc, const float* ep_flat)
{
  const int t = t0 + U;
  const f32x2 expB = exq;   // exp(logB[t, pair]), computed last step

  // ---- issue memory early (R10 ordering) ----
  int tn = t + 16; tn = (tn < T_LEN) ? tn : (T_LEN - 1);
  lbp[U] = *reinterpret_cast<const f32x2*>(pB + (size_t)tn * KST);

  // slow gauge: once per block, read proxy max, set K and Ctot
  if (U == 0) {
    float M = m_sc[0];
    M = fminf(fmaxf(M, 1e-30f), 1e30f);   // exact free gauge; NaN firewall
    float l2 = __log2f(M);
    Ctot += l2 * 0.69314718056f;
    float K = __builtin_amdgcn_exp2f(l2 * -0.0625f);   // M^(-1/16)
    Kv = f32x2{K, K};
  }

  // shat(t-1): this chunk's 8 source-pairs (4 b128, conflict-free)
  const float* sp = s_flat + (U & 1) * SROW + 20 * cc;
  const float4 v0 = *(const float4*)(sp + 0),  v1 = *(const float4*)(sp + 4);
  const float4 v2 = *(const float4*)(sp + 8),  v3 = *(const float4*)(sp + 12);

  // ee rotation read for t+1 (byte-offset walk; skew changes at U==15)
  if (U == 15) {
    int rn = (t0 + 16 - cc16) & 127;
    int cl = (c2 + 4 * ((rn >> 4) & 7)) & 127;
    off = rn * 512 + cl * 4;
  } else {
    off = (off + 512) & 0xFFFF;
  }
  const f32x2 ne =
      *reinterpret_cast<const f32x2*>(reinterpret_cast<const char*>(ep_flat) + off);

  // ---- duration dot: 16 pk over state-paired ring (2 chains) ----
  f32x2 da = pk_mul(qq[0], ee[(0 - U) & 15]);
  f32x2 db = pk_mul(qq[1], ee[(1 - U) & 15]);
#pragma unroll
  for (int k = 2; k < 16; k += 2) {
    pk_fma(da, qq[k],     ee[(k - U) & 15]);
    pk_fma(db, qq[k + 1], ee[(k + 1 - U) & 15]);
  }
  f32x2 dp = da + db;

  // ---- gauge update: one pk_mul by the in-register block constant ----
  psi = pk_mul(psi, pk_mul(expB, Kv));

  // ---- matvec: 16 pk, dests (2m,2m+1) in pk lanes, src-broadcast ----
  f32x2 ma = {0.0f, 0.0f}, mb = {0.0f, 0.0f};
  { f32x2 vp = {v0.x, v0.y}; pk_fma_blo(ma, Apl[0], vp); pk_fma_bhi(mb, Aph[0], vp); }
  { f32x2 vp = {v0.z, v0.w}; pk_fma_blo(ma, Apl[1], vp); pk_fma_bhi(mb, Aph[1], vp); }
  { f32x2 vp = {v1.x, v1.y}; pk_fma_blo(ma, Apl[2], vp); pk_fma_bhi(mb, Aph[2], vp); }
  { f32x2 vp = {v1.z, v1.w}; pk_fma_blo(ma, Apl[3], vp); pk_fma_bhi(mb, Aph[3], vp); }
  { f32x2 vp = {v2.x, v2.y}; pk_fma_blo(ma, Apl[4], vp); pk_fma_bhi(mb, Aph[4], vp); }
  { f32x2 vp = {v2.z, v2.w}; pk_fma_blo(ma, Apl[5], vp); pk_fma_bhi(mb, Aph[5], vp); }
  { f32x2 vp = {v3.x, v3.y}; pk_fma_blo(ma, Apl[6], vp); pk_fma_bhi(mb, Aph[6], vp); }
  { f32x2 vp = {v3.z, v3.w}; pk_fma_blo(ma, Apl[7], vp); pk_fma_bhi(mb, Aph[7], vp); }
  f32x2 mp = ma + mb;

  // ---- reduce over 8 chunk lanes (bits 0..2): xor1, xor2, mirror-8 ----
  dp = dpp_addv<0xB1>(dp); dp = dpp_addv<0x4E>(dp); dp = dpp_addv<0x141>(dp);
  mp = dpp_addv<0xB1>(mp); mp = dpp_addv<0x4E>(mp); mp = dpp_addv<0x141>(mp);

  // ---- insert pair + shat pair (group-uniform) ----
  f32x2 Qins = pk_mul(mp, invpsi);
  if (U == 0) { if (t0 == 0) Qins = pexpp; }
  f32x2 sacc = dp;
  pk_fma(sacc, Qins, expD0p);
  const f32x2 s = pk_mul(sacc, psi);

  // publish shat pair early: one b64 per group
  if (cc == 0)
    *reinterpret_cast<f32x2*>(s_flat + ((U + 1) & 1) * SROW + swaddr) = s;

  // proxy max: ONCE per block (U==15), wave 0, R10-verified chain
  if (U == 15 && w == 0) {
    float sm = fmaxf(s.x, s.y);
    sm = fmaxf(sm, dpp_mov<0x140>(sm));   // row_mirror
    sm = fmaxf(sm, dpp_mov<0x142>(sm));   // row_bcast15
    sm = fmaxf(sm, dpp_mov<0x143>(sm));   // row_bcast31 -> lane 63
    if (L == 63) m_sc[0] = sm;
  }

  // ---- thread-local tail ----
  // exp for NEXT step (loaded 15 steps ago -> arrived)
  exq.x = __expf(lbp[(U + 1) & 15].x);
  exq.y = __expf(lbp[(U + 1) & 15].y);

  // ring insert: slot p = t&127 -> chunk sel = (t>>4)&7, reg U
  if (sel == cc) qq[U] = Qins;

  // commit ee rotation (old slot fully consumed by the dot above)
  ee[(15 - U) & 15] = ne;

  // fold gauge into ring every 16 steps
  if (U == 15) {
#pragma unroll
    for (int k = 0; k < 16; ++k) qq[k] = pk_mul(qq[k], psi);
    psi = f32x2{1.0f, 1.0f};
  }
  invpsi.x = __builtin_amdgcn_rcpf(psi.x);
  invpsi.y = __builtin_amdgcn_rcpf(psi.y);

  skeep = s;
  barrier_nodrain();
}

__global__ __launch_bounds__(NTHR, 1) void hsmm_fwd_kernel(
    const float* __restrict__ logB_all,
    const float* __restrict__ logpi,
    const float* __restrict__ logA,
    const float* __restrict__ logD,
    float* __restrict__ out)
{
  const int tid = threadIdx.x;
  const int L   = tid & 63;
  const int w   = tid >> 6;
  const int cc  = L & 7;            // source chunk (8 lanes per group)
  const int g   = L >> 3;           // dest group 0..7
  const int m   = 8 * w + g;        // pair index: states (2m, 2m+1)
  const int j0  = 2 * m;
  const int b   = blockIdx.x;
  const float* __restrict__ pB = logB_all + (size_t)b * T_LEN * KST + j0;

  // epair[d][col(m,d) + {0,1}] = (expD[2m][d], expD[2m+1][d]);
  // col(m,d) = (2m + 4*((d>>4)&7)) & 127. Row 0 zeroed (stale-slot kill).
  __shared__ __align__(16) float epair[128 * 128];
  __shared__ __align__(16) float s_lds[2 * SROW];  // pair-interleaved shat
  __shared__ float m_sc[1];                        // block proxy max
  __shared__ float fin[8];

  // ---- init ----
  for (int idx = tid; idx < 128 * 128; idx += NTHR) {
    int d = idx >> 7, r = idx & 127;
    int mm = r >> 1, hb = r & 1;
    int col = ((2 * mm + 4 * ((d >> 4) & 7)) & 127) + hb;
    epair[(d << 7) + col] = (d == 0) ? 0.0f : __expf(logD[(2 * mm + hb) * 128 + d]);
  }
  if (tid < 2 * SROW) s_lds[tid] = 0.0f;
  if (tid == 0) m_sc[0] = 1.0f;

  // matvec constants: chunk cc covers source pairs mm = 8cc+k -> states
  // (16cc+2k, 16cc+2k+1). Apl = even-source coeffs, Aph = odd-source.
  f32x2 Apl[8], Aph[8];
#pragma unroll
  for (int k = 0; k < 8; ++k) {
    int se = 16 * cc + 2 * k;
    Apl[k].x = __expf(logA[se * KST + j0]);
    Apl[k].y = __expf(logA[se * KST + j0 + 1]);
    Aph[k].x = __expf(logA[(se + 1) * KST + j0]);
    Aph[k].y = __expf(logA[(se + 1) * KST + j0 + 1]);
  }
  const f32x2 expD0p = {__expf(logD[j0 * 128]), __expf(logD[(j0 + 1) * 128])};
  const f32x2 pexpp  = {__expf(logpi[j0]), __expf(logpi[j0 + 1])};
  const int   swaddr = 20 * w + 2 * g;   // pair m at 20*(m>>3) + 2*(m&7)
  const int   c2     = 2 * m;            // epair column base
  const int   cc16   = 16 * cc;

  f32x2 qq[16];
#pragma unroll
  for (int k = 0; k < 16; ++k) qq[k] = f32x2{0.0f, 0.0f};

  __syncthreads();  // table + buffers ready

  // ee init for t=0: ee[k] = epair row (-(16cc+k))&127, col base c2
  f32x2 ee[16];
#pragma unroll
  for (int k = 0; k < 16; ++k) {
    int rA = (-(cc16 + k)) & 127;
    int cl = (c2 + 4 * ((rA >> 4) & 7)) & 127;
    ee[k] = *reinterpret_cast<const f32x2*>(&epair[(rA << 7) + cl]);
  }

  // rotation byte offset, pre-decremented (body adds 512 -> row t+1-16cc)
  int off;
  {
    int r0 = (-cc16) & 127;
    int cl = (c2 + 4 * ((r0 >> 4) & 7)) & 127;
    off = r0 * 512 + cl * 4;
  }

  // logB pair prefetch ring (16 ahead)
  f32x2 lbp[16];
#pragma unroll
  for (int u = 0; u < 16; ++u)
    lbp[u] = *reinterpret_cast<const f32x2*>(pB + (size_t)u * KST);

  f32x2 psi = {1.0f, 1.0f}, invpsi = {1.0f, 1.0f};
  f32x2 Kv  = {1.0f, 1.0f};
  float Ctot = 0.0f;
  f32x2 skeep = {0.0f, 0.0f};
  f32x2 exq = {__expf(lbp[0].x), __expf(lbp[0].y)};

#pragma unroll 1
  for (int t0 = 0; t0 < T_LEN; t0 += 16) {
    const int sel = (t0 >> 4) & 7;   // ring chunk receiving this block
#define STEP(U) step_body<U>(t0, cc, w, L, sel, c2, cc16, pB, qq, Apl, Aph,   \
                             ee, lbp, off, psi, invpsi, exq, Kv, Ctot,        \
                             skeep, expD0p, pexpp, swaddr, s_lds, m_sc, epair)
    STEP(0);  STEP(1);  STEP(2);  STEP(3);
    STEP(4);  STEP(5);  STEP(6);  STEP(7);
    STEP(8);  STEP(9);  STEP(10); STEP(11);
    STEP(12); STEP(13); STEP(14); STEP(15);
#undef STEP
  }

  // ---- final: out[b] = Ctot + log sum_j shat[j] (each pair once: cc==0) --
  float v = (cc == 0) ? (skeep.x + skeep.y) : 0.0f;
  v += __shfl_xor(v, 8);  v += __shfl_xor(v, 16); v += __shfl_xor(v, 32);
  if (L == 0) fin[w] = v;
  __syncthreads();
  if (tid == 0) {
    float tot = 0.0f;
#pragma unroll
    for (int i = 0; i < 8; ++i) tot += fin[i];
    out[b] = Ctot + __logf(tot);
  }
}

extern "C" void kernel_launch(void* const* d_in, const int* in_sizes, int n_in,
                              void* d_out, int out_size, void* d_ws, size_t ws_size,
                              hipStream_t stream) {
  const float* logB  = (const float*)d_in[0];
  const float* logpi = (const float*)d_in[1];
  const float* logA  = (const float*)d_in[2];
  const float* logD  = (const float*)d_in[3];
  float* out = (float*)d_out;
  const int B = out_size;  // 32
  hipLaunchKernelGGL(hsmm_fwd_kernel, dim3(B), dim3(NTHR), 0, stream,
                     logB, logpi, logA, logD, out);
}